// Round 24
// baseline (60.938 us; speedup 1.0000x reference)
//
#include <hip/hip_runtime.h>
#include <cstdint>
#include <cstddef>
#include <math.h>

#define CAP 4096        // fallback path LDS size
#define KMAX 64
#define NCHUNK 32
#define LCAP 1024       // per-chunk LDS candidate buffer
#define RMAX 5          // float4 per thread (c4 <= 1280)
#define NLAD 6
#define SPEC 2          // speculative store rung (d = 3.0 scaled)
#define NEG_INF (-3.402823466e+38f)

typedef float v4f __attribute__((ext_vector_type(4)));
typedef unsigned long long ull;

__device__ __forceinline__ unsigned int fkey(float f) {
    unsigned int u = __float_as_uint(f);
    return (u & 0x80000000u) ? ~u : (u | 0x80000000u);
}
__device__ __forceinline__ float unkey(unsigned int k) {
    unsigned int u = (k & 0x80000000u) ? (k & 0x7FFFFFFFu) : ~k;
    return __uint_as_float(u);
}
__device__ __forceinline__ float dmarg(float T) {
    return fabsf(T) * 6e-7f + 1e-30f;
}

// ---- wave-level bitonic primitives (64 lanes, u64 keys, DESC) — proven ----
__device__ __forceinline__ ull sort64_desc(ull key, int lane) {
    #pragma unroll
    for (int size = 2; size <= 64; size <<= 1) {
        #pragma unroll
        for (int stride = size >> 1; stride > 0; stride >>= 1) {
            ull other = __shfl_xor(key, stride, 64);
            bool lower = ((lane & stride) == 0);
            bool descBlk = ((lane & size) == 0);
            bool keepMax = (descBlk == lower);
            bool gt = key > other;
            key = (keepMax == gt) ? key : other;
        }
    }
    return key;
}
__device__ __forceinline__ ull clean64_desc(ull key, int lane) {
    #pragma unroll
    for (int stride = 32; stride > 0; stride >>= 1) {
        ull other = __shfl_xor(key, stride, 64);
        bool lower = ((lane & stride) == 0);
        bool gt = key > other;
        key = (lower == gt) ? key : other;
    }
    return key;
}

// thread-0 serial tail (f32-faithful, bit-exact vs gold since R7)
__device__ __forceinline__ int tail_select(
        const float* s_cv, float* s_p, int ncand, int kwant, int topk,
        float topp) {
    int kp = 0;
    if (ncand > 0) {
        int klim = min(kwant, ncand);
        if (topk > 0 && ncand >= kwant) {
            const float kth = s_cv[kwant - 1];
            while (klim < ncand && klim < KMAX && s_cv[klim] == kth) klim++;
        }
        const float sv0 = s_cv[0];
        float e[KMAX];
        for (int j = 0; j < klim; ++j)
            e[j] = (float)exp((double)(s_cv[j] - sv0));
        float r[8] = {0.f, 0.f, 0.f, 0.f, 0.f, 0.f, 0.f, 0.f};
        for (int i = 0; i < 128; i += 8)
            #pragma unroll
            for (int j2 = 0; j2 < 8; ++j2) {
                int idx = i + j2;
                if (idx < klim) r[j2] = r[j2] + e[idx];
            }
        const float S = ((r[0] + r[1]) + (r[2] + r[3])) +
                        ((r[4] + r[5]) + (r[6] + r[7]));
        if (topp > 0.f) {
            float cdf = 0.f;
            for (int j = 0; j < klim; ++j) {
                if (j > 0 && cdf > topp) break;
                kp++;
                cdf = cdf + (float)(e[j] / S);
            }
        } else {
            kp = klim;
        }
        float D = 0.f;
        for (int j = 0; j < kp; ++j) D = D + e[j];
        if (!(D > 0.f)) D = 1.f;
        for (int j = 0; j < kp; ++j) s_p[j] = e[j] / D;
    }
    return kp;
}

// LDS bitonic sort (fallback paths only): value desc, index asc
__device__ __forceinline__ void bitonic_sort(
        float* s_cv, unsigned int* s_ci, int sortn, int tid, int nthr) {
    for (unsigned int size = 2; size <= (unsigned)sortn; size <<= 1) {
        for (unsigned int stride = size >> 1; stride > 0; stride >>= 1) {
            for (int i = tid; i < sortn / 2; i += nthr) {
                unsigned int ui = (unsigned int)i;
                unsigned int pos = 2u * ui - (ui & (stride - 1u));
                unsigned int a = pos, b = pos + stride;
                float va = s_cv[a], vb = s_cv[b];
                unsigned int ia = s_ci[a], ib = s_ci[b];
                bool aBeforeB = (va > vb) || (va == vb && ia < ib);
                bool bBeforeA = (vb > va) || (vb == va && ib < ia);
                bool descBlock = ((pos & size) == 0u);
                bool doSwap = descBlock ? bBeforeA : aBeforeB;
                if (doSwap) {
                    s_cv[a] = vb; s_cv[b] = va;
                    s_ci[a] = ib; s_ci[b] = ia;
                }
            }
            __syncthreads();
        }
    }
}

// ---------------- Kernel A: register chunk, fused count+spec-store ----------
__global__ __launch_bounds__(256, 8) void k_stream(
        const float* __restrict__ in, float* __restrict__ out,
        ull* __restrict__ ws_keys, float* __restrict__ ws_max,
        unsigned int* __restrict__ ws_flag, const float* __restrict__ tempP,
        int nv4) {
    __shared__ float s_w[4];
    __shared__ float s_cm;
    __shared__ unsigned int s_lcnt[3];     // packed 2x16-bit counts per word
    __shared__ unsigned int s_cnt;
    __shared__ float2 s_ent[LCAP];
    __shared__ ull s_lists[4][64];

    const int row = blockIdx.x / NCHUNK;
    const int chunk = blockIdx.x % NCHUNK;
    const int c4 = (nv4 + NCHUNK - 1) / NCHUNK;
    const int base = chunk * c4;
    const int end = min(nv4, base + c4);
    const int tid = (int)threadIdx.x;
    const int wid = tid >> 6, lane = tid & 63;
    const float t = tempP[0];
    const bool doT = (t > 0.f);
    const float tt = doT ? t : 1.f;

    const float4* in4 = (const float4*)in + (size_t)row * nv4;
    float4* out4 = (float4*)out + (size_t)row * nv4;
    const v4f z4 = {0.f, 0.f, 0.f, 0.f};

    // ---- load chunk to registers + fused NT zero of output ----
    float4 r[RMAX];
    #pragma unroll
    for (int u = 0; u < RMAX; ++u) {
        int idx = base + u * 256 + tid;
        bool inb = (idx < end);
        if (inb) r[u] = in4[idx];
        else r[u] = make_float4(NEG_INF, NEG_INF, NEG_INF, NEG_INF);
        if (inb) __builtin_nontemporal_store(z4, (v4f*)(out4 + idx));
    }

    // ---- exact chunk max ----
    float m = NEG_INF;
    #pragma unroll
    for (int u = 0; u < RMAX; ++u)
        m = fmaxf(m, fmaxf(fmaxf(r[u].x, r[u].y), fmaxf(r[u].z, r[u].w)));
    #pragma unroll
    for (int off = 32; off; off >>= 1)
        m = fmaxf(m, __shfl_xor(m, off));
    if (lane == 0) s_w[wid] = m;
    __syncthreads();
    if (tid == 0) {
        s_cm = fmaxf(fmaxf(s_w[0], s_w[1]), fmaxf(s_w[2], s_w[3]));
        ws_max[blockIdx.x] = s_cm;
        s_lcnt[0] = 0u; s_lcnt[1] = 0u; s_lcnt[2] = 0u;
        s_cnt = 0u;
    }
    __syncthreads();
    const float cm = s_cm;

    // ---- rung thresholds (depths 1.6..5.1 scaled, ratio-per-rung ~9.8) ----
    float Tc[NLAD];
    #pragma unroll
    for (int j = 0; j < NLAD; ++j) {
        const float dj = (1.6f + 0.7f * j) * tt;
        const float T = cm - dj;
        Tc[j] = T - 2.f * dmarg(T);
    }

    // ---- ONE pass: packed counts at 6 rungs + speculative store at SPEC ----
    unsigned int p01 = 0u, p23 = 0u, p45 = 0u;
    #pragma unroll
    for (int u = 0; u < RMAX; ++u) {
        const float xs[4] = {r[u].x, r[u].y, r[u].z, r[u].w};
        #pragma unroll
        for (int c2 = 0; c2 < 4; ++c2) {
            const float x = xs[c2];
            const bool b2 = (x >= Tc[2]);
            p01 += ((x >= Tc[0]) ? 1u : 0u) + ((x >= Tc[1]) ? 0x10000u : 0u);
            p23 += (b2 ? 1u : 0u) + ((x >= Tc[3]) ? 0x10000u : 0u);
            p45 += ((x >= Tc[4]) ? 1u : 0u) + ((x >= Tc[5]) ? 0x10000u : 0u);
            if (b2) {
                unsigned int slot = atomicAdd(&s_cnt, 1u);
                if (slot < (unsigned)LCAP) {
                    float2 p;
                    p.x = x;
                    p.y = __uint_as_float((unsigned)(4 * (base + u * 256 + tid) + c2));
                    s_ent[slot] = p;
                }
            }
        }
    }
    #pragma unroll
    for (int off = 32; off; off >>= 1) {
        p01 += (unsigned int)__shfl_xor(p01, off);
        p23 += (unsigned int)__shfl_xor(p23, off);
        p45 += (unsigned int)__shfl_xor(p45, off);
    }
    if (lane == 0) {
        atomicAdd(&s_lcnt[0], p01);
        atomicAdd(&s_lcnt[1], p23);
        atomicAdd(&s_lcnt[2], p45);
    }
    __syncthreads();

    // ---- unpack counts; pick shallowest rung with count >= 64 ----
    unsigned int cj[NLAD];
    cj[0] = s_lcnt[0] & 0xFFFFu;  cj[1] = s_lcnt[0] >> 16;
    cj[2] = s_lcnt[1] & 0xFFFFu;  cj[3] = s_lcnt[1] >> 16;
    cj[4] = s_lcnt[2] & 0xFFFFu;  cj[5] = s_lcnt[2] >> 16;
    const int nelem = (end - base) * 4;
    const int minneed = min(64, nelem);
    int jstar = -1;
    #pragma unroll
    for (int j = 0; j < NLAD; ++j)
        if (jstar < 0 && (int)cj[j] >= minneed) jstar = j;
    const bool ok = (jstar >= 0) && (cj[jstar] <= (unsigned)LCAP);
    // speculative store valid iff jstar == SPEC (s_ent already = {x >= Tc[SPEC]})
    const bool spec_ok = ok && (jstar == SPEC);
    __syncthreads();

    // ---- retry store only if the speculative rung wasn't the pick ----
    if (ok && !spec_ok) {
        if (tid == 0) s_cnt = 0u;
        __syncthreads();
        const float Tsel = Tc[jstar];
        #pragma unroll
        for (int u = 0; u < RMAX; ++u) {
            const float xs[4] = {r[u].x, r[u].y, r[u].z, r[u].w};
            #pragma unroll
            for (int c2 = 0; c2 < 4; ++c2) {
                if (xs[c2] >= Tsel) {
                    unsigned int slot = atomicAdd(&s_cnt, 1u);
                    if (slot < (unsigned)LCAP) {
                        float2 p;
                        p.x = xs[c2];
                        p.y = __uint_as_float((unsigned)(4 * (base + u * 256 + tid) + c2));
                        s_ent[slot] = p;
                    }
                }
            }
        }
        __syncthreads();
    }
    const int ncap = ok ? (int)min(s_cnt, (unsigned)LCAP) : 0;

    // ---- chunk exact top-64 by scaled key (wave bitonic) ----
    const int nb = (ncap + 255) >> 8;
    ull run = 0ull;
    for (int b = 0; b < nb; ++b) {
        int s = wid * (nb * 64) + b * 64 + lane;
        ull k = 0ull;
        if (s < ncap) {
            float2 p = s_ent[s];
            float sv = doT ? (p.x / t) : p.x;
            k = ((ull)fkey(sv) << 32) | (ull)(~__float_as_uint(p.y));
        }
        k = sort64_desc(k, lane);
        if (b == 0) run = k;
        else {
            ull rev = __shfl(k, 63 - lane, 64);
            run = (run > rev) ? run : rev;
            run = clean64_desc(run, lane);
        }
    }
    s_lists[wid][lane] = run;
    __syncthreads();
    if (wid < 2) {
        ull a = s_lists[wid][lane];
        ull bb = s_lists[wid + 2][63 - lane];
        ull cc = (a > bb) ? a : bb;
        cc = clean64_desc(cc, lane);
        s_lists[wid][lane] = cc;
    }
    __syncthreads();
    if (wid == 0) {
        ull a = s_lists[0][lane];
        ull bb = s_lists[1][63 - lane];
        ull cc = (a > bb) ? a : bb;
        cc = clean64_desc(cc, lane);
        ws_keys[(size_t)blockIdx.x * 64 + lane] = cc;
    }
    if (tid == 0) ws_flag[blockIdx.x] = ok ? 0u : 1u;
}

// ---------------- Kernel B: merge 32 sorted lists + tail + scatter ----------
__global__ __launch_bounds__(1024) void k_select(
        const float* __restrict__ in, float* __restrict__ out,
        const ull* __restrict__ ws_keys, const float* __restrict__ ws_max,
        const unsigned int* __restrict__ ws_flag,
        const float* __restrict__ tempP, const int* __restrict__ topkP,
        const float* __restrict__ toppP, int V, int nv4) {
    __shared__ ull s_lists[16][64];
    __shared__ float s_cv[CAP];
    __shared__ unsigned int s_ci[CAP];
    __shared__ unsigned int s_cnt;
    __shared__ float s_p[KMAX];
    __shared__ int s_kp;
    __shared__ int s_nc;

    const int row = blockIdx.x;
    const int tid = (int)threadIdx.x;
    const int nthr = (int)blockDim.x;
    const int wid = tid >> 6, lane = tid & 63;

    const float t = tempP[0];
    const bool doT = (t > 0.f);
    const float tt = doT ? t : 1.f;
    int topk = topkP[0];
    if (topk < 0 || topk > V) topk = 0;
    const float topp = toppP[0];
    const int kwant = (topk > 0) ? min(topk, KMAX) : KMAX;

    bool overflow = false;
    float M = NEG_INF;
    #pragma unroll
    for (int c = 0; c < NCHUNK; ++c) {
        if (ws_flag[row * NCHUNK + c] != 0u) overflow = true;
        M = fmaxf(M, ws_max[row * NCHUNK + c]);
    }

    int ncand;
    if (!overflow) {
        // fast path: each of 16 waves pre-merges 2 sorted lists, then tree
        const ull* keys = ws_keys + (size_t)row * NCHUNK * 64;
        ull mrun = keys[(size_t)(2 * wid) * 64 + lane];
        {
            ull k = keys[(size_t)(2 * wid + 1) * 64 + lane];
            ull rev = __shfl(k, 63 - lane, 64);
            mrun = (mrun > rev) ? mrun : rev;
            mrun = clean64_desc(mrun, lane);
        }
        s_lists[wid][lane] = mrun;
        __syncthreads();
        #pragma unroll
        for (int half = 8; half >= 1; half >>= 1) {
            if (wid < half) {
                ull a = s_lists[wid][lane];
                ull bb = s_lists[wid + half][63 - lane];
                ull c = (a > bb) ? a : bb;
                c = clean64_desc(c, lane);
                s_lists[wid][lane] = c;
            }
            __syncthreads();
        }
        if (wid == 0) {
            ull k = s_lists[0][lane];
            s_cv[lane] = unkey((unsigned)(k >> 32));       // scaled value
            s_ci[lane] = ~(unsigned)(k & 0xFFFFFFFFull);   // token index
            unsigned long long bal = __ballot(k != 0ull);
            if (lane == 0) s_nc = (int)__popcll(bal);
        }
        __syncthreads();
        ncand = s_nc;
    } else {
        // safety net: full-row adaptive collect + LDS sort (proven)
        const float4* in4 = (const float4*)in + (size_t)row * nv4;
        unsigned int cnt = 0;
        float dcut = 3.0f * tt;
        for (int round = 0; round < 14; ++round) {
            if (tid == 0) s_cnt = 0u;
            __syncthreads();
            const float T = M - dcut;
            for (int i2 = tid; i2 < nv4; i2 += nthr) {
                float4 v = in4[i2];
                const float xs[4] = {v.x, v.y, v.z, v.w};
                #pragma unroll
                for (int c2 = 0; c2 < 4; ++c2) {
                    if (xs[c2] >= T) {
                        unsigned int slot = atomicAdd(&s_cnt, 1u);
                        if (slot < (unsigned)CAP) {
                            s_cv[slot] = xs[c2];
                            s_ci[slot] = (unsigned int)(4 * i2 + c2);
                        }
                    }
                }
            }
            __syncthreads();
            cnt = s_cnt;
            __syncthreads();
            if (cnt >= (unsigned)kwant && cnt <= (unsigned)CAP) break;
            if (round == 13) break;
            dcut = (cnt < (unsigned)kwant) ? (dcut * 2.0f) : (dcut * 0.4f);
        }
        ncand = (int)min(cnt, (unsigned)CAP);
        if (doT) {
            for (int j = tid; j < ncand; j += nthr) s_cv[j] = s_cv[j] / t;
        }
        int sortn = 128;
        while (sortn < ncand) sortn <<= 1;
        for (int s = ncand + tid; s < sortn; s += nthr) {
            s_cv[s] = NEG_INF;
            s_ci[s] = 0xFFFFFFFFu;
        }
        __syncthreads();
        bitonic_sort(s_cv, s_ci, sortn, tid, nthr);
    }

    if (tid == 0) s_kp = tail_select(s_cv, s_p, ncand, kwant, topk, topp);
    __syncthreads();

    if (tid < s_kp) {
        unsigned int tok = s_ci[tid];
        if (tok < (unsigned int)V)
            out[(size_t)row * V + tok] = s_p[tid];
    }
}

// ---------------- monolithic fallback (R7-proven, scaled space) -------------
__global__ __launch_bounds__(1024) void k_row_mono(
        const float* __restrict__ in, float* __restrict__ out,
        const float* __restrict__ tempP, const int* __restrict__ topkP,
        const float* __restrict__ toppP, int V, int nv4) {
    __shared__ float s_red[1024];
    __shared__ float s_cv[CAP];
    __shared__ unsigned int s_ci[CAP];
    __shared__ unsigned int s_cnt;
    __shared__ float s_p[KMAX];
    __shared__ int s_kp;

    const int row = blockIdx.x;
    const int tid = (int)threadIdx.x;
    const int nthr = (int)blockDim.x;

    const float t = tempP[0];
    const bool doT = (t > 0.f);
    int topk = topkP[0];
    if (topk < 0 || topk > V) topk = 0;
    const float topp = toppP[0];

    const float4* in4 = (const float4*)in + (size_t)row * nv4;
    float4* out4 = (float4*)out + (size_t)row * nv4;
    float m = NEG_INF;
    for (int i = tid; i < nv4; i += nthr) {
        float4 v = in4[i];
        out4[i] = make_float4(0.f, 0.f, 0.f, 0.f);
        float a = doT ? v.x / t : v.x;
        float b = doT ? v.y / t : v.y;
        float c = doT ? v.z / t : v.z;
        float d = doT ? v.w / t : v.w;
        m = fmaxf(m, fmaxf(fmaxf(a, b), fmaxf(c, d)));
    }
    s_red[tid] = m;
    __syncthreads();
    for (int s = 512; s > 0; s >>= 1) {
        if (tid < s) s_red[tid] = fmaxf(s_red[tid], s_red[tid + s]);
        __syncthreads();
    }
    const float M = s_red[0];
    __syncthreads();

    const int kwant = (topk > 0) ? min(topk, KMAX) : KMAX;
    float dcut = 2.5f;
    unsigned int cnt = 0;
    for (int round = 0; round < 14; ++round) {
        if (tid == 0) s_cnt = 0u;
        __syncthreads();
        const float T = M - dcut;
        for (int i = tid; i < nv4; i += nthr) {
            float4 v = in4[i];
            float xs[4];
            xs[0] = doT ? v.x / t : v.x;
            xs[1] = doT ? v.y / t : v.y;
            xs[2] = doT ? v.z / t : v.z;
            xs[3] = doT ? v.w / t : v.w;
            #pragma unroll
            for (int c2 = 0; c2 < 4; ++c2) {
                if (xs[c2] >= T) {
                    unsigned int slot = atomicAdd(&s_cnt, 1u);
                    if (slot < (unsigned)CAP) {
                        s_cv[slot] = xs[c2];
                        s_ci[slot] = (unsigned int)(4 * i + c2);
                    }
                }
            }
        }
        __syncthreads();
        cnt = s_cnt;
        __syncthreads();
        if (cnt >= (unsigned)kwant && cnt <= (unsigned)CAP) break;
        if (round == 13) break;
        dcut = (cnt < (unsigned)kwant) ? (dcut * 2.0f) : (dcut * 0.4f);
    }
    const int ncand = (int)min(cnt, (unsigned)CAP);

    int sortn = 128;
    while (sortn < ncand) sortn <<= 1;
    for (int s = ncand + tid; s < sortn; s += nthr) {
        s_cv[s] = NEG_INF;
        s_ci[s] = 0xFFFFFFFFu;
    }
    __syncthreads();
    bitonic_sort(s_cv, s_ci, sortn, tid, nthr);

    if (tid == 0) s_kp = tail_select(s_cv, s_p, ncand, kwant, topk, topp);
    __syncthreads();

    if (tid < s_kp) {
        unsigned int tok = s_ci[tid];
        if (tok < (unsigned int)V)
            out[(size_t)row * V + tok] = s_p[tid];
    }
}

extern "C" void kernel_launch(void* const* d_in, const int* in_sizes, int n_in,
                              void* d_out, int out_size, void* d_ws, size_t ws_size,
                              hipStream_t stream) {
    const float* in = (const float*)d_in[0];
    const float* tempP = (const float*)d_in[2];
    const int* topkP = (const int*)d_in[3];
    const float* toppP = (const float*)d_in[4];
    float* out = (float*)d_out;

    int B = (n_in > 1 && in_sizes[1] > 0) ? in_sizes[1] : 128;
    int V = in_sizes[0] / B;
    int nv4 = V / 4;
    const int BN = B * NCHUNK;
    const int c4 = (nv4 + NCHUNK - 1) / NCHUNK;

    // ws: keys (BN*64 ull) | max (BN f32) | flag (BN u32)
    const size_t off_max = (size_t)BN * 64 * 8;
    const size_t off_flag = off_max + (size_t)BN * 4;
    const size_t need = off_flag + (size_t)BN * 4;
    if (ws_size >= need && c4 <= RMAX * 256) {
        ull* ws_keys = (ull*)d_ws;
        float* ws_max = (float*)((char*)d_ws + off_max);
        unsigned int* ws_flag = (unsigned int*)((char*)d_ws + off_flag);
        k_stream<<<BN, 256, 0, stream>>>(in, out, ws_keys, ws_max, ws_flag,
                                         tempP, nv4);
        k_select<<<B, 1024, 0, stream>>>(in, out, ws_keys, ws_max, ws_flag,
                                         tempP, topkP, toppP, V, nv4);
    } else {
        k_row_mono<<<B, 1024, 0, stream>>>(in, out, tempP, topkP, toppP, V, nv4);
    }
}

// Round 25
// 57.223 us; speedup vs baseline: 1.0649x; 1.0649x over previous
//
#include <hip/hip_runtime.h>
#include <cstdint>
#include <cstddef>
#include <math.h>

#define CAP 4096        // fallback path LDS size
#define KMAX 64
#define NCHUNK 32
#define LCAP 1024       // per-chunk LDS candidate buffer
#define RMAX 5          // float4 per thread (c4 <= 1280)
#define NLAD 6
#define NEG_INF (-3.402823466e+38f)

typedef float v4f __attribute__((ext_vector_type(4)));
typedef unsigned long long ull;

__device__ __forceinline__ unsigned int fkey(float f) {
    unsigned int u = __float_as_uint(f);
    return (u & 0x80000000u) ? ~u : (u | 0x80000000u);
}
__device__ __forceinline__ float unkey(unsigned int k) {
    unsigned int u = (k & 0x80000000u) ? (k & 0x7FFFFFFFu) : ~k;
    return __uint_as_float(u);
}
__device__ __forceinline__ float dmarg(float T) {
    return fabsf(T) * 6e-7f + 1e-30f;
}

// ---- wave-level bitonic primitives (64 lanes, u64 keys, DESC) — proven ----
__device__ __forceinline__ ull sort64_desc(ull key, int lane) {
    #pragma unroll
    for (int size = 2; size <= 64; size <<= 1) {
        #pragma unroll
        for (int stride = size >> 1; stride > 0; stride >>= 1) {
            ull other = __shfl_xor(key, stride, 64);
            bool lower = ((lane & stride) == 0);
            bool descBlk = ((lane & size) == 0);
            bool keepMax = (descBlk == lower);
            bool gt = key > other;
            key = (keepMax == gt) ? key : other;
        }
    }
    return key;
}
__device__ __forceinline__ ull clean64_desc(ull key, int lane) {
    #pragma unroll
    for (int stride = 32; stride > 0; stride >>= 1) {
        ull other = __shfl_xor(key, stride, 64);
        bool lower = ((lane & stride) == 0);
        bool gt = key > other;
        key = (lower == gt) ? key : other;
    }
    return key;
}

// thread-0 serial tail (f32-faithful, bit-exact vs gold since R7)
__device__ __forceinline__ int tail_select(
        const float* s_cv, float* s_p, int ncand, int kwant, int topk,
        float topp) {
    int kp = 0;
    if (ncand > 0) {
        int klim = min(kwant, ncand);
        if (topk > 0 && ncand >= kwant) {
            const float kth = s_cv[kwant - 1];
            while (klim < ncand && klim < KMAX && s_cv[klim] == kth) klim++;
        }
        const float sv0 = s_cv[0];
        float e[KMAX];
        for (int j = 0; j < klim; ++j)
            e[j] = (float)exp((double)(s_cv[j] - sv0));
        float r[8] = {0.f, 0.f, 0.f, 0.f, 0.f, 0.f, 0.f, 0.f};
        for (int i = 0; i < 128; i += 8)
            #pragma unroll
            for (int j2 = 0; j2 < 8; ++j2) {
                int idx = i + j2;
                if (idx < klim) r[j2] = r[j2] + e[idx];
            }
        const float S = ((r[0] + r[1]) + (r[2] + r[3])) +
                        ((r[4] + r[5]) + (r[6] + r[7]));
        if (topp > 0.f) {
            float cdf = 0.f;
            for (int j = 0; j < klim; ++j) {
                if (j > 0 && cdf > topp) break;
                kp++;
                cdf = cdf + (float)(e[j] / S);
            }
        } else {
            kp = klim;
        }
        float D = 0.f;
        for (int j = 0; j < kp; ++j) D = D + e[j];
        if (!(D > 0.f)) D = 1.f;
        for (int j = 0; j < kp; ++j) s_p[j] = e[j] / D;
    }
    return kp;
}

// LDS bitonic sort (fallback paths only): value desc, index asc
__device__ __forceinline__ void bitonic_sort(
        float* s_cv, unsigned int* s_ci, int sortn, int tid, int nthr) {
    for (unsigned int size = 2; size <= (unsigned)sortn; size <<= 1) {
        for (unsigned int stride = size >> 1; stride > 0; stride >>= 1) {
            for (int i = tid; i < sortn / 2; i += nthr) {
                unsigned int ui = (unsigned int)i;
                unsigned int pos = 2u * ui - (ui & (stride - 1u));
                unsigned int a = pos, b = pos + stride;
                float va = s_cv[a], vb = s_cv[b];
                unsigned int ia = s_ci[a], ib = s_ci[b];
                bool aBeforeB = (va > vb) || (va == vb && ia < ib);
                bool bBeforeA = (vb > va) || (vb == va && ib < ia);
                bool descBlock = ((pos & size) == 0u);
                bool doSwap = descBlock ? bBeforeA : aBeforeB;
                if (doSwap) {
                    s_cv[a] = vb; s_cv[b] = va;
                    s_ci[a] = ib; s_ci[b] = ia;
                }
            }
            __syncthreads();
        }
    }
}

// ---------------- Kernel A: register chunk, 6-rung one-pass select ----------
__global__ __launch_bounds__(256, 8) void k_stream(
        const float* __restrict__ in, float* __restrict__ out,
        ull* __restrict__ ws_keys, float* __restrict__ ws_max,
        unsigned int* __restrict__ ws_flag, const float* __restrict__ tempP,
        int nv4) {
    __shared__ float s_w[4];
    __shared__ float s_cm;
    __shared__ unsigned int s_lcnt[NLAD];
    __shared__ unsigned int s_cnt;
    __shared__ float2 s_ent[LCAP];
    __shared__ ull s_lists[4][64];

    const int row = blockIdx.x / NCHUNK;
    const int chunk = blockIdx.x % NCHUNK;
    const int c4 = (nv4 + NCHUNK - 1) / NCHUNK;
    const int base = chunk * c4;
    const int end = min(nv4, base + c4);
    const int tid = (int)threadIdx.x;
    const int wid = tid >> 6, lane = tid & 63;
    const float t = tempP[0];
    const bool doT = (t > 0.f);
    const float tt = doT ? t : 1.f;

    const float4* in4 = (const float4*)in + (size_t)row * nv4;
    float4* out4 = (float4*)out + (size_t)row * nv4;
    const v4f z4 = {0.f, 0.f, 0.f, 0.f};

    // ---- load chunk to registers + fused NT zero of output ----
    float4 r[RMAX];
    #pragma unroll
    for (int u = 0; u < RMAX; ++u) {
        int idx = base + u * 256 + tid;
        bool inb = (idx < end);
        if (inb) r[u] = in4[idx];
        else r[u] = make_float4(NEG_INF, NEG_INF, NEG_INF, NEG_INF);
        if (inb) __builtin_nontemporal_store(z4, (v4f*)(out4 + idx));
    }

    // ---- exact chunk max ----
    float m = NEG_INF;
    #pragma unroll
    for (int u = 0; u < RMAX; ++u)
        m = fmaxf(m, fmaxf(fmaxf(r[u].x, r[u].y), fmaxf(r[u].z, r[u].w)));
    #pragma unroll
    for (int off = 32; off; off >>= 1)
        m = fmaxf(m, __shfl_xor(m, off));
    if (lane == 0) s_w[wid] = m;
    __syncthreads();
    if (tid == 0) {
        s_cm = fmaxf(fmaxf(s_w[0], s_w[1]), fmaxf(s_w[2], s_w[3]));
        ws_max[blockIdx.x] = s_cm;
        #pragma unroll
        for (int j = 0; j < NLAD; ++j) s_lcnt[j] = 0u;
        s_cnt = 0u;
    }
    __syncthreads();
    const float cm = s_cm;

    // ---- rung thresholds (depths 1.6..5.1 scaled, ratio-per-rung ~9.8) ----
    float Tc[NLAD];
    #pragma unroll
    for (int j = 0; j < NLAD; ++j) {
        const float dj = (1.6f + 0.7f * j) * tt;
        const float T = cm - dj;
        Tc[j] = T - 2.f * dmarg(T);
    }

    // ---- ONE pass: per-thread counts at all 6 rungs (pure VALU) ----
    unsigned int c[NLAD] = {0u, 0u, 0u, 0u, 0u, 0u};
    #pragma unroll
    for (int u = 0; u < RMAX; ++u) {
        const float xs[4] = {r[u].x, r[u].y, r[u].z, r[u].w};
        #pragma unroll
        for (int c2 = 0; c2 < 4; ++c2) {
            #pragma unroll
            for (int j = 0; j < NLAD; ++j)
                c[j] += (xs[c2] >= Tc[j]) ? 1u : 0u;
        }
    }
    #pragma unroll
    for (int j = 0; j < NLAD; ++j) {
        #pragma unroll
        for (int off = 32; off; off >>= 1)
            c[j] += (unsigned int)__shfl_xor(c[j], off);
    }
    if (lane == 0) {
        #pragma unroll
        for (int j = 0; j < NLAD; ++j) atomicAdd(&s_lcnt[j], c[j]);
    }
    __syncthreads();

    // ---- pick shallowest rung with count >= 64 ----
    const int nelem = (end - base) * 4;
    const int minneed = min(64, nelem);
    int jstar = -1;
    #pragma unroll
    for (int j = 0; j < NLAD; ++j)
        if (jstar < 0 && (int)s_lcnt[j] >= minneed) jstar = j;
    bool ok = (jstar >= 0) && (s_lcnt[jstar] <= (unsigned)LCAP);
    const float Tsel = ok ? Tc[jstar] : Tc[0];
    __syncthreads();

    // ---- one store pass at chosen rung ----
    if (ok) {
        #pragma unroll
        for (int u = 0; u < RMAX; ++u) {
            const float xs[4] = {r[u].x, r[u].y, r[u].z, r[u].w};
            #pragma unroll
            for (int c2 = 0; c2 < 4; ++c2) {
                if (xs[c2] >= Tsel) {
                    unsigned int slot = atomicAdd(&s_cnt, 1u);
                    if (slot < (unsigned)LCAP) {
                        float2 p;
                        p.x = xs[c2];
                        p.y = __uint_as_float((unsigned)(4 * (base + u * 256 + tid) + c2));
                        s_ent[slot] = p;
                    }
                }
            }
        }
    }
    __syncthreads();
    const int ncap = (int)min(s_cnt, (unsigned)LCAP);

    // ---- chunk exact top-64 by scaled key (wave bitonic) ----
    const int nb = (ncap + 255) >> 8;
    ull run = 0ull;
    for (int b = 0; b < nb; ++b) {
        int s = wid * (nb * 64) + b * 64 + lane;
        ull k = 0ull;
        if (s < ncap) {
            float2 p = s_ent[s];
            float sv = doT ? (p.x / t) : p.x;
            k = ((ull)fkey(sv) << 32) | (ull)(~__float_as_uint(p.y));
        }
        k = sort64_desc(k, lane);
        if (b == 0) run = k;
        else {
            ull rev = __shfl(k, 63 - lane, 64);
            run = (run > rev) ? run : rev;
            run = clean64_desc(run, lane);
        }
    }
    s_lists[wid][lane] = run;
    __syncthreads();
    if (wid < 2) {
        ull a = s_lists[wid][lane];
        ull bb = s_lists[wid + 2][63 - lane];
        ull cc = (a > bb) ? a : bb;
        cc = clean64_desc(cc, lane);
        s_lists[wid][lane] = cc;
    }
    __syncthreads();
    if (wid == 0) {
        ull a = s_lists[0][lane];
        ull bb = s_lists[1][63 - lane];
        ull cc = (a > bb) ? a : bb;
        cc = clean64_desc(cc, lane);
        ws_keys[(size_t)blockIdx.x * 64 + lane] = cc;
    }
    if (tid == 0) ws_flag[blockIdx.x] = ok ? 0u : 1u;
}

// ---------------- Kernel B: merge 32 sorted lists + tail + scatter ----------
__global__ __launch_bounds__(1024) void k_select(
        const float* __restrict__ in, float* __restrict__ out,
        const ull* __restrict__ ws_keys, const float* __restrict__ ws_max,
        const unsigned int* __restrict__ ws_flag,
        const float* __restrict__ tempP, const int* __restrict__ topkP,
        const float* __restrict__ toppP, int V, int nv4) {
    __shared__ ull s_lists[16][64];
    __shared__ float s_cv[CAP];
    __shared__ unsigned int s_ci[CAP];
    __shared__ unsigned int s_cnt;
    __shared__ float s_p[KMAX];
    __shared__ int s_kp;
    __shared__ int s_nc;

    const int row = blockIdx.x;
    const int tid = (int)threadIdx.x;
    const int nthr = (int)blockDim.x;
    const int wid = tid >> 6, lane = tid & 63;

    const float t = tempP[0];
    const bool doT = (t > 0.f);
    const float tt = doT ? t : 1.f;
    int topk = topkP[0];
    if (topk < 0 || topk > V) topk = 0;
    const float topp = toppP[0];
    const int kwant = (topk > 0) ? min(topk, KMAX) : KMAX;

    bool overflow = false;
    float M = NEG_INF;
    #pragma unroll
    for (int c = 0; c < NCHUNK; ++c) {
        if (ws_flag[row * NCHUNK + c] != 0u) overflow = true;
        M = fmaxf(M, ws_max[row * NCHUNK + c]);
    }

    int ncand;
    if (!overflow) {
        // fast path: each of 16 waves pre-merges 2 sorted lists, then tree
        const ull* keys = ws_keys + (size_t)row * NCHUNK * 64;
        ull mrun = keys[(size_t)(2 * wid) * 64 + lane];
        {
            ull k = keys[(size_t)(2 * wid + 1) * 64 + lane];
            ull rev = __shfl(k, 63 - lane, 64);
            mrun = (mrun > rev) ? mrun : rev;
            mrun = clean64_desc(mrun, lane);
        }
        s_lists[wid][lane] = mrun;
        __syncthreads();
        #pragma unroll
        for (int half = 8; half >= 1; half >>= 1) {
            if (wid < half) {
                ull a = s_lists[wid][lane];
                ull bb = s_lists[wid + half][63 - lane];
                ull c = (a > bb) ? a : bb;
                c = clean64_desc(c, lane);
                s_lists[wid][lane] = c;
            }
            __syncthreads();
        }
        if (wid == 0) {
            ull k = s_lists[0][lane];
            s_cv[lane] = unkey((unsigned)(k >> 32));       // scaled value
            s_ci[lane] = ~(unsigned)(k & 0xFFFFFFFFull);   // token index
            unsigned long long bal = __ballot(k != 0ull);
            if (lane == 0) s_nc = (int)__popcll(bal);
        }
        __syncthreads();
        ncand = s_nc;
    } else {
        // safety net: full-row adaptive collect + LDS sort (proven)
        const float4* in4 = (const float4*)in + (size_t)row * nv4;
        unsigned int cnt = 0;
        float dcut = 3.0f * tt;
        for (int round = 0; round < 14; ++round) {
            if (tid == 0) s_cnt = 0u;
            __syncthreads();
            const float T = M - dcut;
            for (int i2 = tid; i2 < nv4; i2 += nthr) {
                float4 v = in4[i2];
                const float xs[4] = {v.x, v.y, v.z, v.w};
                #pragma unroll
                for (int c2 = 0; c2 < 4; ++c2) {
                    if (xs[c2] >= T) {
                        unsigned int slot = atomicAdd(&s_cnt, 1u);
                        if (slot < (unsigned)CAP) {
                            s_cv[slot] = xs[c2];
                            s_ci[slot] = (unsigned int)(4 * i2 + c2);
                        }
                    }
                }
            }
            __syncthreads();
            cnt = s_cnt;
            __syncthreads();
            if (cnt >= (unsigned)kwant && cnt <= (unsigned)CAP) break;
            if (round == 13) break;
            dcut = (cnt < (unsigned)kwant) ? (dcut * 2.0f) : (dcut * 0.4f);
        }
        ncand = (int)min(cnt, (unsigned)CAP);
        if (doT) {
            for (int j = tid; j < ncand; j += nthr) s_cv[j] = s_cv[j] / t;
        }
        int sortn = 128;
        while (sortn < ncand) sortn <<= 1;
        for (int s = ncand + tid; s < sortn; s += nthr) {
            s_cv[s] = NEG_INF;
            s_ci[s] = 0xFFFFFFFFu;
        }
        __syncthreads();
        bitonic_sort(s_cv, s_ci, sortn, tid, nthr);
    }

    if (tid == 0) s_kp = tail_select(s_cv, s_p, ncand, kwant, topk, topp);
    __syncthreads();

    if (tid < s_kp) {
        unsigned int tok = s_ci[tid];
        if (tok < (unsigned int)V)
            out[(size_t)row * V + tok] = s_p[tid];
    }
}

// ---------------- monolithic fallback (R7-proven, scaled space) -------------
__global__ __launch_bounds__(1024) void k_row_mono(
        const float* __restrict__ in, float* __restrict__ out,
        const float* __restrict__ tempP, const int* __restrict__ topkP,
        const float* __restrict__ toppP, int V, int nv4) {
    __shared__ float s_red[1024];
    __shared__ float s_cv[CAP];
    __shared__ unsigned int s_ci[CAP];
    __shared__ unsigned int s_cnt;
    __shared__ float s_p[KMAX];
    __shared__ int s_kp;

    const int row = blockIdx.x;
    const int tid = (int)threadIdx.x;
    const int nthr = (int)blockDim.x;

    const float t = tempP[0];
    const bool doT = (t > 0.f);
    int topk = topkP[0];
    if (topk < 0 || topk > V) topk = 0;
    const float topp = toppP[0];

    const float4* in4 = (const float4*)in + (size_t)row * nv4;
    float4* out4 = (float4*)out + (size_t)row * nv4;
    float m = NEG_INF;
    for (int i = tid; i < nv4; i += nthr) {
        float4 v = in4[i];
        out4[i] = make_float4(0.f, 0.f, 0.f, 0.f);
        float a = doT ? v.x / t : v.x;
        float b = doT ? v.y / t : v.y;
        float c = doT ? v.z / t : v.z;
        float d = doT ? v.w / t : v.w;
        m = fmaxf(m, fmaxf(fmaxf(a, b), fmaxf(c, d)));
    }
    s_red[tid] = m;
    __syncthreads();
    for (int s = 512; s > 0; s >>= 1) {
        if (tid < s) s_red[tid] = fmaxf(s_red[tid], s_red[tid + s]);
        __syncthreads();
    }
    const float M = s_red[0];
    __syncthreads();

    const int kwant = (topk > 0) ? min(topk, KMAX) : KMAX;
    float dcut = 2.5f;
    unsigned int cnt = 0;
    for (int round = 0; round < 14; ++round) {
        if (tid == 0) s_cnt = 0u;
        __syncthreads();
        const float T = M - dcut;
        for (int i = tid; i < nv4; i += nthr) {
            float4 v = in4[i];
            float xs[4];
            xs[0] = doT ? v.x / t : v.x;
            xs[1] = doT ? v.y / t : v.y;
            xs[2] = doT ? v.z / t : v.z;
            xs[3] = doT ? v.w / t : v.w;
            #pragma unroll
            for (int c2 = 0; c2 < 4; ++c2) {
                if (xs[c2] >= T) {
                    unsigned int slot = atomicAdd(&s_cnt, 1u);
                    if (slot < (unsigned)CAP) {
                        s_cv[slot] = xs[c2];
                        s_ci[slot] = (unsigned int)(4 * i + c2);
                    }
                }
            }
        }
        __syncthreads();
        cnt = s_cnt;
        __syncthreads();
        if (cnt >= (unsigned)kwant && cnt <= (unsigned)CAP) break;
        if (round == 13) break;
        dcut = (cnt < (unsigned)kwant) ? (dcut * 2.0f) : (dcut * 0.4f);
    }
    const int ncand = (int)min(cnt, (unsigned)CAP);

    int sortn = 128;
    while (sortn < ncand) sortn <<= 1;
    for (int s = ncand + tid; s < sortn; s += nthr) {
        s_cv[s] = NEG_INF;
        s_ci[s] = 0xFFFFFFFFu;
    }
    __syncthreads();
    bitonic_sort(s_cv, s_ci, sortn, tid, nthr);

    if (tid == 0) s_kp = tail_select(s_cv, s_p, ncand, kwant, topk, topp);
    __syncthreads();

    if (tid < s_kp) {
        unsigned int tok = s_ci[tid];
        if (tok < (unsigned int)V)
            out[(size_t)row * V + tok] = s_p[tid];
    }
}

extern "C" void kernel_launch(void* const* d_in, const int* in_sizes, int n_in,
                              void* d_out, int out_size, void* d_ws, size_t ws_size,
                              hipStream_t stream) {
    const float* in = (const float*)d_in[0];
    const float* tempP = (const float*)d_in[2];
    const int* topkP = (const int*)d_in[3];
    const float* toppP = (const float*)d_in[4];
    float* out = (float*)d_out;

    int B = (n_in > 1 && in_sizes[1] > 0) ? in_sizes[1] : 128;
    int V = in_sizes[0] / B;
    int nv4 = V / 4;
    const int BN = B * NCHUNK;
    const int c4 = (nv4 + NCHUNK - 1) / NCHUNK;

    // ws: keys (BN*64 ull) | max (BN f32) | flag (BN u32)
    const size_t off_max = (size_t)BN * 64 * 8;
    const size_t off_flag = off_max + (size_t)BN * 4;
    const size_t need = off_flag + (size_t)BN * 4;
    if (ws_size >= need && c4 <= RMAX * 256) {
        ull* ws_keys = (ull*)d_ws;
        float* ws_max = (float*)((char*)d_ws + off_max);
        unsigned int* ws_flag = (unsigned int*)((char*)d_ws + off_flag);
        k_stream<<<BN, 256, 0, stream>>>(in, out, ws_keys, ws_max, ws_flag,
                                         tempP, nv4);
        k_select<<<B, 1024, 0, stream>>>(in, out, ws_keys, ws_max, ws_flag,
                                         tempP, topkP, toppP, V, nv4);
    } else {
        k_row_mono<<<B, 1024, 0, stream>>>(in, out, tempP, topkP, toppP, V, nv4);
    }
}